// Round 14
// baseline (258.692 us; speedup 1.0000x reference)
//
#include <hip/hip_runtime.h>

typedef __attribute__((ext_vector_type(8))) short bf16x8;
typedef __attribute__((ext_vector_type(4))) float f32x4;

#define NBLK   16          // nodes per tile
#define DIMF   1152        // floats per node row
#define NTILE  6250        // 100000 / 16, exact
#define GRIDSZ 512         // persistent, stride grid
#define ROWU   1168        // padded ushort row stride: 2336 B == 8 dwords mod 32
                           // -> ds_read_b128 bank = (8*lq+4*lg)%32, 2-way max (free)
#define WNUM   49152       // 3 * 128 * 128

// round-to-nearest-even f32 -> bf16 bits
static __device__ __forceinline__ unsigned short f2bf(float f) {
    unsigned int u = __builtin_bit_cast(unsigned int, f);
    return (unsigned short)((u + 0x7FFFu + ((u >> 16) & 1u)) >> 16);
}

// One-time prep: wb[((s*4+t)*4+lg)*1024 + v*8 + e] = bf16(pw * W[32t+8lg+e][v])
// so a lane's (s,t) A-fragment is ONE coalesced 16B load at ((s*4+t)*4+lg)*1024+(v)*8.
__global__ __launch_bounds__(256)
void prep_w(const float* __restrict__ w, unsigned short* __restrict__ wb) {
    int d = blockIdx.x * 256 + threadIdx.x;
    if (d >= WNUM) return;
    int e  = d & 7;
    int v  = (d >> 3) & 127;
    int lg = (d >> 10) & 3;
    int t  = (d >> 12) & 3;
    int s  = d >> 14;
    int u  = 32 * t + 8 * lg + e;
    wb[d] = f2bf(0.08838834764831845f * w[s * 16384 + u * 128 + v]);
}

__global__ __launch_bounds__(512, 4)   // 4 waves/EU -> 128-reg budget, 2 blocks/CU
void seglin_kernel(const float* __restrict__ x, const unsigned short* __restrict__ wb,
                   const float* __restrict__ b, float* __restrict__ out) {
    // LDS: per node, 9 planes of 128 u-contiguous bf16
    __shared__ unsigned short xs[2][NBLK][ROWU];

    const int tid  = threadIdx.x;
    const int wv   = tid >> 6;
    const int lane = tid & 63;
    const int lq   = lane & 15;       // node col n (B); A row v_local
    const int lg   = lane >> 4;       // k-group 0..3
    const int v0   = wv * 16;

    const int sn = tid >> 5;          // staging node 0..15
    const int st = tid & 31;          // staging u-chunk 0..31

    // per-(s,t) A-frag byte base (element offset): ((s*4+t)*4+lg)*1024 + (v0+lq)*8
    const int fbase = (lg << 10) + ((v0 + lq) << 3);

    float biasr[4];
    #pragma unroll
    for (int e = 0; e < 4; ++e) biasr[e] = b[v0 + lg * 4 + e];

    // Staged tile: 36 f32 loaded at loop-TOP, consumed at loop-END (R9/R10 law).
    float4 g0, g1[3], g2[5];

#define STAGE_LOAD(TILE) do {                                                   \
        const float* src = x + ((long)(TILE) * NBLK + sn) * DIMF;               \
        g0    = *reinterpret_cast<const float4*>(src + 4 * st);                 \
        g1[0] = *reinterpret_cast<const float4*>(src + 128 + 12 * st);          \
        g1[1] = *reinterpret_cast<const float4*>(src + 128 + 12 * st + 4);      \
        g1[2] = *reinterpret_cast<const float4*>(src + 128 + 12 * st + 8);      \
        g2[0] = *reinterpret_cast<const float4*>(src + 512 + 20 * st);          \
        g2[1] = *reinterpret_cast<const float4*>(src + 512 + 20 * st + 4);      \
        g2[2] = *reinterpret_cast<const float4*>(src + 512 + 20 * st + 8);      \
        g2[3] = *reinterpret_cast<const float4*>(src + 512 + 20 * st + 12);     \
        g2[4] = *reinterpret_cast<const float4*>(src + 512 + 20 * st + 16);     \
    } while (0)

    // seg1 plane i pos u=4st+e <- f1[3e+i]; seg2 plane i <- f2[5e+i]
#define STAGE_WRITE(BUF) do {                                                   \
        unsigned short* dst = &xs[BUF][sn][0];                                  \
        { ushort4 h;                                                            \
          h.x = f2bf(g0.x); h.y = f2bf(g0.y); h.z = f2bf(g0.z); h.w = f2bf(g0.w); \
          *reinterpret_cast<ushort4*>(dst + 4 * st) = h; }                      \
        float f1[12];                                                           \
        f1[0]=g1[0].x; f1[1]=g1[0].y; f1[2]=g1[0].z; f1[3]=g1[0].w;             \
        f1[4]=g1[1].x; f1[5]=g1[1].y; f1[6]=g1[1].z; f1[7]=g1[1].w;             \
        f1[8]=g1[2].x; f1[9]=g1[2].y; f1[10]=g1[2].z; f1[11]=g1[2].w;           \
        _Pragma("unroll")                                                       \
        for (int i = 0; i < 3; ++i) {                                           \
            ushort4 h;                                                          \
            h.x = f2bf(f1[0 + i]); h.y = f2bf(f1[3 + i]);                       \
            h.z = f2bf(f1[6 + i]); h.w = f2bf(f1[9 + i]);                       \
            *reinterpret_cast<ushort4*>(dst + 128 + (i << 7) + 4 * st) = h;     \
        }                                                                       \
        float f2[20];                                                           \
        f2[0]=g2[0].x; f2[1]=g2[0].y; f2[2]=g2[0].z; f2[3]=g2[0].w;             \
        f2[4]=g2[1].x; f2[5]=g2[1].y; f2[6]=g2[1].z; f2[7]=g2[1].w;             \
        f2[8]=g2[2].x; f2[9]=g2[2].y; f2[10]=g2[2].z; f2[11]=g2[2].w;           \
        f2[12]=g2[3].x; f2[13]=g2[3].y; f2[14]=g2[3].z; f2[15]=g2[3].w;         \
        f2[16]=g2[4].x; f2[17]=g2[4].y; f2[18]=g2[4].z; f2[19]=g2[4].w;         \
        _Pragma("unroll")                                                       \
        for (int i = 0; i < 5; ++i) {                                           \
            ushort4 h;                                                          \
            h.x = f2bf(f2[0 + i]);  h.y = f2bf(f2[5 + i]);                      \
            h.z = f2bf(f2[10 + i]); h.w = f2bf(f2[15 + i]);                     \
            *reinterpret_cast<ushort4*>(dst + 512 + (i << 7) + 4 * st) = h;     \
        }                                                                       \
    } while (0)

    // ---- prologue ----
    long tile = blockIdx.x;
    STAGE_LOAD(tile);
    STAGE_WRITE(0);
    __syncthreads();

    int cur = 0;
    for (; tile < NTILE; tile += GRIDSZ) {
        const bool has_next = (tile + GRIDSZ) < NTILE;

        // ---- A-frags from L2 FIRST (12 x dwordx4, ~200cy), then HBM staging
        //      loads. vmcnt ordering: frag consumers never wait on staging. ----
        bf16x8 af[3][4];
        #pragma unroll
        for (int s = 0; s < 3; ++s)
            #pragma unroll
            for (int t = 0; t < 4; ++t)
                af[s][t] = *reinterpret_cast<const bf16x8*>(
                    wb + (((s * 4 + t) << 12) + fbase));

        if (has_next) STAGE_LOAD(tile + GRIDSZ);

        const unsigned short* row = &xs[cur][lq][0];
        float* orow = out + (tile * NBLK + lq) * (long)DIMF;
        const int vb = v0 + lg * 4;

        // ===== group A: seg0 =====
        {
            f32x4 a0 = {0.f, 0.f, 0.f, 0.f};
            #pragma unroll
            for (int t = 0; t < 4; ++t) {
                bf16x8 bf = *reinterpret_cast<const bf16x8*>(row + 32 * t + lg * 8);
                a0 = __builtin_amdgcn_mfma_f32_16x16x32_bf16(af[0][t], bf, a0, 0, 0, 0);
            }
            float4 o0;
            o0.x = a0[0] + biasr[0];
            o0.y = a0[1] + biasr[1];
            o0.z = a0[2] + biasr[2];
            o0.w = a0[3] + biasr[3];
            *reinterpret_cast<float4*>(orow + vb) = o0;
        }

        // ===== group B: seg1 =====
        {
            f32x4 aB[3];
            #pragma unroll
            for (int j = 0; j < 3; ++j) { f32x4 z = {0.f,0.f,0.f,0.f}; aB[j] = z; }
            #pragma unroll
            for (int t = 0; t < 4; ++t) {
                const int u0 = 32 * t + lg * 8;
                #pragma unroll
                for (int j = 0; j < 3; ++j) {
                    bf16x8 bf = *reinterpret_cast<const bf16x8*>(row + ((1 + j) << 7) + u0);
                    aB[j] = __builtin_amdgcn_mfma_f32_16x16x32_bf16(af[1][t], bf, aB[j], 0, 0, 0);
                }
            }
            float* p1o = orow + 128 + 3 * vb;   // p=3e+i -> aB[p%3][p/3]
            #pragma unroll
            for (int k = 0; k < 3; ++k) {
                float4 o;
                o.x = aB[(4 * k + 0) % 3][(4 * k + 0) / 3];
                o.y = aB[(4 * k + 1) % 3][(4 * k + 1) / 3];
                o.z = aB[(4 * k + 2) % 3][(4 * k + 2) / 3];
                o.w = aB[(4 * k + 3) % 3][(4 * k + 3) / 3];
                *reinterpret_cast<float4*>(p1o + 4 * k) = o;
            }
        }

        // ===== group C: seg2 =====
        {
            f32x4 aC[5];
            #pragma unroll
            for (int j = 0; j < 5; ++j) { f32x4 z = {0.f,0.f,0.f,0.f}; aC[j] = z; }
            #pragma unroll
            for (int t = 0; t < 4; ++t) {
                const int u0 = 32 * t + lg * 8;
                #pragma unroll
                for (int j = 0; j < 5; ++j) {
                    bf16x8 bf = *reinterpret_cast<const bf16x8*>(row + ((4 + j) << 7) + u0);
                    aC[j] = __builtin_amdgcn_mfma_f32_16x16x32_bf16(af[2][t], bf, aC[j], 0, 0, 0);
                }
            }
            float* p2o = orow + 512 + 5 * vb;   // p=5e+i -> aC[p%5][p/5]
            #pragma unroll
            for (int k = 0; k < 5; ++k) {
                float4 o;
                o.x = aC[(4 * k + 0) % 5][(4 * k + 0) / 5];
                o.y = aC[(4 * k + 1) % 5][(4 * k + 1) / 5];
                o.z = aC[(4 * k + 2) % 5][(4 * k + 2) / 5];
                o.w = aC[(4 * k + 3) % 5][(4 * k + 3) / 5];
                *reinterpret_cast<float4*>(p2o + 4 * k) = o;
            }
        }

        // ---- retire staged regs into LDS (loads issued a full period ago) ----
        if (has_next) STAGE_WRITE(cur ^ 1);

        // Relaxed barrier: only LDS ops must drain; global loads/stores keep
        // flowing across it (counted-vmcnt discipline).
        asm volatile("s_waitcnt lgkmcnt(0)\n\ts_barrier" ::: "memory");
        cur ^= 1;
    }
#undef STAGE_LOAD
#undef STAGE_WRITE
}

extern "C" void kernel_launch(void* const* d_in, const int* in_sizes, int n_in,
                              void* d_out, int out_size, void* d_ws, size_t ws_size,
                              hipStream_t stream) {
    const float* x = (const float*)d_in[0];
    const float* w = (const float*)d_in[1];
    const float* b = (const float*)d_in[2];
    float* outp = (float*)d_out;
    unsigned short* wb = (unsigned short*)d_ws;   // 96 KB bf16 W, frag-major layout

    prep_w<<<dim3((WNUM + 255) / 256), dim3(256), 0, stream>>>(w, wb);
    seglin_kernel<<<dim3(GRIDSZ), dim3(512), 0, stream>>>(x, wb, b, outp);
}

// Round 15
// 191.190 us; speedup vs baseline: 1.3531x; 1.3531x over previous
//
#include <hip/hip_runtime.h>

typedef __attribute__((ext_vector_type(8))) short bf16x8;
typedef __attribute__((ext_vector_type(4))) float f32x4;

#define NBLK   16          // nodes per tile
#define DIMF   1152        // floats per node row
#define NTILE  6250        // 100000 / 16, exact
#define GRIDSZ 512         // persistent, stride grid
#define ROWU   1168        // padded ushort row stride: 2336 B == 8 dwords mod 32
                           // -> ds_read_b128 bank = (8*lq+4*lg)%32, 2-way max (free)
                           // [R14 verified: SQ_LDS_BANK_CONFLICT 7.2M -> 0]
#define WNUM   49152       // 3 * 128 * 128

// round-to-nearest-even f32 -> bf16 bits
static __device__ __forceinline__ unsigned short f2bf(float f) {
    unsigned int u = __builtin_bit_cast(unsigned int, f);
    return (unsigned short)((u + 0x7FFFu + ((u >> 16) & 1u)) >> 16);
}

// One-time prep: wb[((s*4+t)*4+lg)*1024 + v*8 + e] = bf16(pw * W[32t+8lg+e][v])
// so a lane's (s,t) A-fragment is ONE coalesced 16B load.
__global__ __launch_bounds__(256)
void prep_w(const float* __restrict__ w, unsigned short* __restrict__ wb) {
    int d = blockIdx.x * 256 + threadIdx.x;
    if (d >= WNUM) return;
    int e  = d & 7;
    int v  = (d >> 3) & 127;
    int lg = (d >> 10) & 3;
    int t  = (d >> 12) & 3;
    int s  = d >> 14;
    int u  = 32 * t + 8 * lg + e;
    wb[d] = f2bf(0.08838834764831845f * w[s * 16384 + u * 128 + v]);
}

__global__ __launch_bounds__(512, 2)   // NO tighter clamp: (512,4) => 64-reg spill (R2/R12/R14)
void seglin_kernel(const float* __restrict__ x, const unsigned short* __restrict__ wb,
                   const float* __restrict__ b, float* __restrict__ out) {
    // LDS: per node, 9 planes of 128 u-contiguous bf16
    __shared__ unsigned short xs[2][NBLK][ROWU];

    const int tid  = threadIdx.x;
    const int wv   = tid >> 6;
    const int lane = tid & 63;
    const int lq   = lane & 15;       // node col n (B); A row v_local
    const int lg   = lane >> 4;       // k-group 0..3
    const int v0   = wv * 16;

    const int sn = tid >> 5;          // staging node 0..15
    const int st = tid & 31;          // staging u-chunk 0..31

    // per-(s,t) A-frag element base: ((s*4+t)*4+lg)*1024 + (v0+lq)*8
    const int fbase = (lg << 10) + ((v0 + lq) << 3);

    float biasr[4];
    #pragma unroll
    for (int e = 0; e < 4; ++e) biasr[e] = b[v0 + lg * 4 + e];

    // Staged tile: 36 f32 loaded at loop-TOP, consumed at loop-END (R9/R10 law).
    float4 g0, g1[3], g2[5];

#define STAGE_LOAD(TILE) do {                                                   \
        const float* src = x + ((long)(TILE) * NBLK + sn) * DIMF;               \
        g0    = *reinterpret_cast<const float4*>(src + 4 * st);                 \
        g1[0] = *reinterpret_cast<const float4*>(src + 128 + 12 * st);          \
        g1[1] = *reinterpret_cast<const float4*>(src + 128 + 12 * st + 4);      \
        g1[2] = *reinterpret_cast<const float4*>(src + 128 + 12 * st + 8);      \
        g2[0] = *reinterpret_cast<const float4*>(src + 512 + 20 * st);          \
        g2[1] = *reinterpret_cast<const float4*>(src + 512 + 20 * st + 4);      \
        g2[2] = *reinterpret_cast<const float4*>(src + 512 + 20 * st + 8);      \
        g2[3] = *reinterpret_cast<const float4*>(src + 512 + 20 * st + 12);     \
        g2[4] = *reinterpret_cast<const float4*>(src + 512 + 20 * st + 16);     \
    } while (0)

    // seg1 plane i pos u=4st+e <- f1[3e+i]; seg2 plane i <- f2[5e+i]
#define STAGE_WRITE(BUF) do {                                                   \
        unsigned short* dst = &xs[BUF][sn][0];                                  \
        { ushort4 h;                                                            \
          h.x = f2bf(g0.x); h.y = f2bf(g0.y); h.z = f2bf(g0.z); h.w = f2bf(g0.w); \
          *reinterpret_cast<ushort4*>(dst + 4 * st) = h; }                      \
        float f1[12];                                                           \
        f1[0]=g1[0].x; f1[1]=g1[0].y; f1[2]=g1[0].z; f1[3]=g1[0].w;             \
        f1[4]=g1[1].x; f1[5]=g1[1].y; f1[6]=g1[1].z; f1[7]=g1[1].w;             \
        f1[8]=g1[2].x; f1[9]=g1[2].y; f1[10]=g1[2].z; f1[11]=g1[2].w;           \
        _Pragma("unroll")                                                       \
        for (int i = 0; i < 3; ++i) {                                           \
            ushort4 h;                                                          \
            h.x = f2bf(f1[0 + i]); h.y = f2bf(f1[3 + i]);                       \
            h.z = f2bf(f1[6 + i]); h.w = f2bf(f1[9 + i]);                       \
            *reinterpret_cast<ushort4*>(dst + 128 + (i << 7) + 4 * st) = h;     \
        }                                                                       \
        float f2[20];                                                           \
        f2[0]=g2[0].x; f2[1]=g2[0].y; f2[2]=g2[0].z; f2[3]=g2[0].w;             \
        f2[4]=g2[1].x; f2[5]=g2[1].y; f2[6]=g2[1].z; f2[7]=g2[1].w;             \
        f2[8]=g2[2].x; f2[9]=g2[2].y; f2[10]=g2[2].z; f2[11]=g2[2].w;           \
        f2[12]=g2[3].x; f2[13]=g2[3].y; f2[14]=g2[3].z; f2[15]=g2[3].w;         \
        f2[16]=g2[4].x; f2[17]=g2[4].y; f2[18]=g2[4].z; f2[19]=g2[4].w;         \
        _Pragma("unroll")                                                       \
        for (int i = 0; i < 5; ++i) {                                           \
            ushort4 h;                                                          \
            h.x = f2bf(f2[0 + i]);  h.y = f2bf(f2[5 + i]);                      \
            h.z = f2bf(f2[10 + i]); h.w = f2bf(f2[15 + i]);                     \
            *reinterpret_cast<ushort4*>(dst + 512 + (i << 7) + 4 * st) = h;     \
        }                                                                       \
    } while (0)

    // ---- prologue ----
    long tile = blockIdx.x;
    STAGE_LOAD(tile);
    STAGE_WRITE(0);
    __syncthreads();

    int cur = 0;
    for (; tile < NTILE; tile += GRIDSZ) {
        const bool has_next = (tile + GRIDSZ) < NTILE;

        // ---- A-frags from L2 FIRST (12 x dwordx4, issue-order before staging
        //      so frag consumers wait at vmcnt(9), never draining staging) ----
        bf16x8 af[3][4];
        #pragma unroll
        for (int s = 0; s < 3; ++s)
            #pragma unroll
            for (int t = 0; t < 4; ++t)
                af[s][t] = *reinterpret_cast<const bf16x8*>(
                    wb + (((s * 4 + t) << 12) + fbase));

        if (has_next) STAGE_LOAD(tile + GRIDSZ);

        const unsigned short* row = &xs[cur][lq][0];
        float* orow = out + (tile * NBLK + lq) * (long)DIMF;
        const int vb = v0 + lg * 4;

        // ===== group A: seg0 =====
        {
            f32x4 a0 = {0.f, 0.f, 0.f, 0.f};
            #pragma unroll
            for (int t = 0; t < 4; ++t) {
                bf16x8 bf = *reinterpret_cast<const bf16x8*>(row + 32 * t + lg * 8);
                a0 = __builtin_amdgcn_mfma_f32_16x16x32_bf16(af[0][t], bf, a0, 0, 0, 0);
            }
            float4 o0;
            o0.x = a0[0] + biasr[0];
            o0.y = a0[1] + biasr[1];
            o0.z = a0[2] + biasr[2];
            o0.w = a0[3] + biasr[3];
            *reinterpret_cast<float4*>(orow + vb) = o0;
        }

        // ===== group B: seg1 =====
        {
            f32x4 aB[3];
            #pragma unroll
            for (int j = 0; j < 3; ++j) { f32x4 z = {0.f,0.f,0.f,0.f}; aB[j] = z; }
            #pragma unroll
            for (int t = 0; t < 4; ++t) {
                const int u0 = 32 * t + lg * 8;
                #pragma unroll
                for (int j = 0; j < 3; ++j) {
                    bf16x8 bf = *reinterpret_cast<const bf16x8*>(row + ((1 + j) << 7) + u0);
                    aB[j] = __builtin_amdgcn_mfma_f32_16x16x32_bf16(af[1][t], bf, aB[j], 0, 0, 0);
                }
            }
            float* p1o = orow + 128 + 3 * vb;   // p=3e+i -> aB[p%3][p/3]
            #pragma unroll
            for (int k = 0; k < 3; ++k) {
                float4 o;
                o.x = aB[(4 * k + 0) % 3][(4 * k + 0) / 3];
                o.y = aB[(4 * k + 1) % 3][(4 * k + 1) / 3];
                o.z = aB[(4 * k + 2) % 3][(4 * k + 2) / 3];
                o.w = aB[(4 * k + 3) % 3][(4 * k + 3) / 3];
                *reinterpret_cast<float4*>(p1o + 4 * k) = o;
            }
        }

        // ===== group C: seg2 =====
        {
            f32x4 aC[5];
            #pragma unroll
            for (int j = 0; j < 5; ++j) { f32x4 z = {0.f,0.f,0.f,0.f}; aC[j] = z; }
            #pragma unroll
            for (int t = 0; t < 4; ++t) {
                const int u0 = 32 * t + lg * 8;
                #pragma unroll
                for (int j = 0; j < 5; ++j) {
                    bf16x8 bf = *reinterpret_cast<const bf16x8*>(row + ((4 + j) << 7) + u0);
                    aC[j] = __builtin_amdgcn_mfma_f32_16x16x32_bf16(af[2][t], bf, aC[j], 0, 0, 0);
                }
            }
            float* p2o = orow + 512 + 5 * vb;   // p=5e+i -> aC[p%5][p/5]
            #pragma unroll
            for (int k = 0; k < 5; ++k) {
                float4 o;
                o.x = aC[(4 * k + 0) % 5][(4 * k + 0) / 5];
                o.y = aC[(4 * k + 1) % 5][(4 * k + 1) / 5];
                o.z = aC[(4 * k + 2) % 5][(4 * k + 2) / 5];
                o.w = aC[(4 * k + 3) % 5][(4 * k + 3) / 5];
                *reinterpret_cast<float4*>(p2o + 4 * k) = o;
            }
        }

        // ---- retire staged regs into LDS (loads issued a full period ago) ----
        if (has_next) STAGE_WRITE(cur ^ 1);

        // Relaxed barrier: only LDS ops must drain; global loads/stores keep
        // flowing across it (counted-vmcnt discipline).
        asm volatile("s_waitcnt lgkmcnt(0)\n\ts_barrier" ::: "memory");
        cur ^= 1;
    }
#undef STAGE_LOAD
#undef STAGE_WRITE
}

extern "C" void kernel_launch(void* const* d_in, const int* in_sizes, int n_in,
                              void* d_out, int out_size, void* d_ws, size_t ws_size,
                              hipStream_t stream) {
    const float* x = (const float*)d_in[0];
    const float* w = (const float*)d_in[1];
    const float* b = (const float*)d_in[2];
    float* outp = (float*)d_out;
    unsigned short* wb = (unsigned short*)d_ws;   // 96 KB bf16 W, frag-major layout

    prep_w<<<dim3((WNUM + 255) / 256), dim3(256), 0, stream>>>(w, wb);
    seglin_kernel<<<dim3(GRIDSZ), dim3(512), 0, stream>>>(x, wb, b, outp);
}